// Round 1
// baseline (477.992 us; speedup 1.0000x reference)
//
#include <hip/hip_runtime.h>
#include <hip/hip_bf16.h>

// Problem constants (from reference)
#define IN_C   602
#define HID_C  256
#define OUT_C  41
#define N_SRC0 256000
#define N_TGT0 10240
#define N_TGT1 1024
#define E0     256000
#define E1     10240

// ---------------- CSR build for layer 1 ----------------

__global__ void count_kernel(const int* __restrict__ dst, int* __restrict__ cnt, int E) {
    int e = blockIdx.x * blockDim.x + threadIdx.x;
    if (e < E) atomicAdd(&cnt[dst[e]], 1);
}

// single block, 256 threads, n = 10240
__global__ void scan_kernel(const int* __restrict__ cnt, int* __restrict__ rowptr,
                            int* __restrict__ cursor, int n) {
    __shared__ int part[256];
    int t = threadIdx.x;
    int chunk = (n + 255) / 256;
    int beg = t * chunk;
    int end = beg + chunk; if (end > n) end = n;
    int s = 0;
    for (int i = beg; i < end; ++i) s += cnt[i];
    part[t] = s;
    __syncthreads();
    if (t == 0) {
        int run = 0;
        for (int i = 0; i < 256; ++i) { int v = part[i]; part[i] = run; run += v; }
        rowptr[n] = run;
    }
    __syncthreads();
    int run = part[t];
    for (int i = beg; i < end; ++i) {
        rowptr[i] = run;
        cursor[i] = run;
        run += cnt[i];
    }
}

__global__ void scatter_kernel(const int* __restrict__ src, const int* __restrict__ dst,
                               int* __restrict__ cursor, int* __restrict__ elist, int E) {
    int e = blockIdx.x * blockDim.x + threadIdx.x;
    if (e < E) {
        int p = atomicAdd(&cursor[dst[e]], 1);
        elist[p] = src[e];
    }
}

// ---------------- layer-1 mean aggregation (pull, CSR) ----------------
// one block (256 threads) per target node; thread t owns channels t, t+256, t+512
__global__ __launch_bounds__(256) void agg0_kernel(
    const float* __restrict__ x, const int* __restrict__ rowptr,
    const int* __restrict__ elist, float* __restrict__ agg)
{
    int t = blockIdx.x;
    int beg = rowptr[t], end = rowptr[t + 1];
    int c0 = threadIdx.x;
    float a0 = 0.f, a1 = 0.f, a2 = 0.f;
    for (int i = beg; i < end; ++i) {
        const float* row = x + (long)elist[i] * IN_C;
        a0 += row[c0];
        if (c0 + 256 < IN_C) a1 += row[c0 + 256];
        if (c0 + 512 < IN_C) a2 += row[c0 + 512];
    }
    int d = end - beg;
    float inv = 1.0f / (float)(d > 1 ? d : 1);
    float* o = agg + (long)t * IN_C;
    o[c0] = a0 * inv;
    if (c0 + 256 < IN_C) o[c0 + 256] = a1 * inv;
    if (c0 + 512 < IN_C) o[c0 + 512] = a2 * inv;
}

// ---------------- layer-1 fused GEMM: h = relu(agg@Wl1 + x@Wr1 + b1) ----------------
// 64x64 tile, 256 threads, each thread 4x4 outputs, fp32
#define BM 64
#define BN 64
#define BK 16

__global__ __launch_bounds__(256) void gemm1_kernel(
    const float* __restrict__ agg, const float* __restrict__ x,
    const float* __restrict__ Wl, const float* __restrict__ Wr,
    const float* __restrict__ bias, float* __restrict__ h)
{
    __shared__ float As[BK][BM + 1];
    __shared__ float Bs[BK][BN + 1];
    int tid = threadIdx.x;
    int tx = tid % 16, ty = tid / 16;
    int bm = blockIdx.x * BM;
    int bn = blockIdx.y * BN;
    float acc[4][4] = {};

    for (int phase = 0; phase < 2; ++phase) {
        const float* A = phase ? x   : agg;   // [*, 602] row-major, stride 602
        const float* B = phase ? Wr  : Wl;    // [602, 256] row-major

        for (int k0 = 0; k0 < IN_C; k0 += BK) {
            // A tile: 64 rows x 16 k, stored transposed As[k][m]
            {
                int r = tid / 4;
                int c = (tid % 4) * 4;
                const float* srcp = A + (long)(bm + r) * IN_C + k0 + c;
                #pragma unroll
                for (int i = 0; i < 4; ++i) {
                    int kk = k0 + c + i;
                    float v = 0.0f;
                    if (kk < IN_C) v = srcp[i];
                    As[c + i][r] = v;
                }
            }
            // B tile: 16 k x 64 n
            {
                int r = tid / 16;
                int c = tid % 16;
                int kk = k0 + r;
                const float* srcp = B + (long)kk * HID_C + bn + c * 4;
                #pragma unroll
                for (int i = 0; i < 4; ++i) {
                    float v = 0.0f;
                    if (kk < IN_C) v = srcp[i];
                    Bs[r][c * 4 + i] = v;
                }
            }
            __syncthreads();
            #pragma unroll
            for (int k = 0; k < BK; ++k) {
                float a[4], b[4];
                #pragma unroll
                for (int i = 0; i < 4; ++i) a[i] = As[k][ty * 4 + i];
                #pragma unroll
                for (int i = 0; i < 4; ++i) b[i] = Bs[k][tx * 4 + i];
                #pragma unroll
                for (int i = 0; i < 4; ++i)
                    #pragma unroll
                    for (int j = 0; j < 4; ++j)
                        acc[i][j] += a[i] * b[j];
            }
            __syncthreads();
        }
    }

    #pragma unroll
    for (int i = 0; i < 4; ++i) {
        int m = bm + ty * 4 + i;
        #pragma unroll
        for (int j = 0; j < 4; ++j) {
            int n = bn + tx * 4 + j;
            float v = acc[i][j] + bias[n];
            h[(long)m * HID_C + n] = v > 0.f ? v : 0.f;
        }
    }
}

// ---------------- layer-2 aggregation (atomic scatter; only 2.6M adds) ----------------

__global__ void agg1_scatter_kernel(const float* __restrict__ h, const int* __restrict__ src,
                                    const int* __restrict__ dst, float* __restrict__ agg, int E) {
    long i = blockIdx.x * (long)blockDim.x + threadIdx.x;
    if (i < (long)E * HID_C) {
        int e = (int)(i >> 8);
        int c = (int)(i & 255);
        atomicAdd(&agg[(long)dst[e] * HID_C + c], h[(long)src[e] * HID_C + c]);
    }
}

__global__ void agg1_div_kernel(float* __restrict__ agg, const int* __restrict__ cnt) {
    int t = blockIdx.x;
    int d = cnt[t];
    float inv = 1.0f / (float)(d > 1 ? d : 1);
    agg[(long)t * HID_C + threadIdx.x] *= inv;
}

// ---------------- layer-2 GEMM + log_softmax fused ----------------
// one block (64 threads = 1 wave) per output row
__global__ __launch_bounds__(64) void out_kernel(
    const float* __restrict__ agg, const float* __restrict__ h,
    const float* __restrict__ Wl, const float* __restrict__ Wr,
    const float* __restrict__ bias, float* __restrict__ out)
{
    __shared__ float arow[HID_C];
    __shared__ float hrow[HID_C];
    __shared__ float o[OUT_C];
    __shared__ float lse;
    int t = blockIdx.x;
    int tid = threadIdx.x;

    for (int i = tid; i < HID_C; i += 64) {
        arow[i] = agg[(long)t * HID_C + i];
        hrow[i] = h[(long)t * HID_C + i];
    }
    __syncthreads();

    if (tid < OUT_C) {
        float v = bias[tid];
        for (int k = 0; k < HID_C; ++k)
            v += arow[k] * Wl[k * OUT_C + tid] + hrow[k] * Wr[k * OUT_C + tid];
        o[tid] = v;
    }
    __syncthreads();
    if (tid == 0) {
        float mx = o[0];
        for (int i = 1; i < OUT_C; ++i) mx = fmaxf(mx, o[i]);
        float s = 0.f;
        for (int i = 0; i < OUT_C; ++i) s += expf(o[i] - mx);
        lse = mx + logf(s);
    }
    __syncthreads();
    if (tid < OUT_C) out[(long)t * OUT_C + tid] = o[tid] - lse;
}

// ---------------- launch ----------------

extern "C" void kernel_launch(void* const* d_in, const int* in_sizes, int n_in,
                              void* d_out, int out_size, void* d_ws, size_t ws_size,
                              hipStream_t stream) {
    const float* x    = (const float*)d_in[0];
    const int*   src0 = (const int*)d_in[1];
    const int*   dst0 = (const int*)d_in[2];
    const int*   src1 = (const int*)d_in[3];
    const int*   dst1 = (const int*)d_in[4];
    const float* Wl1  = (const float*)d_in[5];
    const float* Wr1  = (const float*)d_in[6];
    const float* b1   = (const float*)d_in[7];
    const float* Wl2  = (const float*)d_in[8];
    const float* Wr2  = (const float*)d_in[9];
    const float* b2   = (const float*)d_in[10];
    float* out = (float*)d_out;

    // workspace layout
    char* ws = (char*)d_ws;
    int* cnt0    = (int*)ws;                    // 10240
    int* rowptr0 = cnt0 + N_TGT0;               // 10241
    int* cursor0 = rowptr0 + N_TGT0 + 1;        // 10240
    int* elist0  = cursor0 + N_TGT0;            // 256000
    int* cnt1    = elist0 + E0;                 // 1024
    float* agg0  = (float*)(cnt1 + N_TGT1);     // 10240*602
    float* h     = agg0 + (long)N_TGT0 * IN_C;  // 10240*256
    float* agg1  = h + (long)N_TGT0 * HID_C;    // 1024*256

    hipMemsetAsync(cnt0, 0, N_TGT0 * sizeof(int), stream);
    hipMemsetAsync(cnt1, 0, N_TGT1 * sizeof(int), stream);
    hipMemsetAsync(agg1, 0, (size_t)N_TGT1 * HID_C * sizeof(float), stream);

    count_kernel<<<(E0 + 255) / 256, 256, 0, stream>>>(dst0, cnt0, E0);
    scan_kernel<<<1, 256, 0, stream>>>(cnt0, rowptr0, cursor0, N_TGT0);
    scatter_kernel<<<(E0 + 255) / 256, 256, 0, stream>>>(src0, dst0, cursor0, elist0, E0);
    agg0_kernel<<<N_TGT0, 256, 0, stream>>>(x, rowptr0, elist0, agg0);

    gemm1_kernel<<<dim3(N_TGT0 / BM, HID_C / BN), 256, 0, stream>>>(agg0, x, Wl1, Wr1, b1, h);

    count_kernel<<<(E1 + 255) / 256, 256, 0, stream>>>(dst1, cnt1, E1);
    agg1_scatter_kernel<<<(int)(((long)E1 * HID_C + 255) / 256), 256, 0, stream>>>(h, src1, dst1, agg1, E1);
    agg1_div_kernel<<<N_TGT1, HID_C, 0, stream>>>(agg1, cnt1);

    out_kernel<<<N_TGT1, 64, 0, stream>>>(agg1, h, Wl2, Wr2, b2, out);
}

// Round 2
// 256.109 us; speedup vs baseline: 1.8664x; 1.8664x over previous
//
#include <hip/hip_runtime.h>
#include <hip/hip_bf16.h>

#define IN_C   602
#define HID_C  256
#define OUT_C  41
#define N_SRC0 256000
#define N_TGT0 10240
#define N_TGT1 1024
#define E0     256000
#define E1     10240
#define KTOT   1216   // 608 (agg, padded) + 608 (x_tgt, padded)

typedef unsigned short u16;
typedef __attribute__((ext_vector_type(4))) float f32x4;
typedef __attribute__((ext_vector_type(8))) short bf16x8;

__device__ __forceinline__ u16 f2bf(float v) {
    union { float f; unsigned u; } c; c.f = v;
    unsigned u = c.u;
    u += 0x7fffu + ((u >> 16) & 1u);   // round-to-nearest-even
    return (u16)(u >> 16);
}

// ---------------- CSR build for layer 1 ----------------

__global__ void count_kernel(const int* __restrict__ dst, int* __restrict__ cnt, int E) {
    int e = blockIdx.x * blockDim.x + threadIdx.x;
    if (e < E) atomicAdd(&cnt[dst[e]], 1);
}

__global__ void scan_kernel(const int* __restrict__ cnt, int* __restrict__ rowptr,
                            int* __restrict__ cursor, int n) {
    __shared__ int part[256];
    int t = threadIdx.x;
    int chunk = (n + 255) / 256;
    int beg = t * chunk;
    int end = beg + chunk; if (end > n) end = n;
    int s = 0;
    for (int i = beg; i < end; ++i) s += cnt[i];
    part[t] = s;
    __syncthreads();
    if (t == 0) {
        int run = 0;
        for (int i = 0; i < 256; ++i) { int v = part[i]; part[i] = run; run += v; }
        rowptr[n] = run;
    }
    __syncthreads();
    int run = part[t];
    for (int i = beg; i < end; ++i) {
        rowptr[i] = run;
        cursor[i] = run;
        run += cnt[i];
    }
}

__global__ void scatter_kernel(const int* __restrict__ src, const int* __restrict__ dst,
                               int* __restrict__ cursor, int* __restrict__ elist, int E) {
    int e = blockIdx.x * blockDim.x + threadIdx.x;
    if (e < E) {
        int p = atomicAdd(&cursor[dst[e]], 1);
        elist[p] = src[e];
    }
}

// ---------------- layer-1 mean aggregation: one wave per target ----------------
// Row = 602 floats = 301 float2 slots. Lane l owns slots l, l+64, l+128, l+192,
// and (l<45) slot 256+l. Output written as bf16 into fused A buffer cols 0..601,
// zeros in pad cols 602..607.
__global__ __launch_bounds__(256) void agg0_kernel(
    const float* __restrict__ x, const int* __restrict__ rowptr,
    const int* __restrict__ elist, u16* __restrict__ A)
{
    int t = blockIdx.x * 4 + (threadIdx.x >> 6);
    int lane = threadIdx.x & 63;
    int beg = rowptr[t], end = rowptr[t + 1];

    float2 a0 = make_float2(0.f, 0.f), a1 = a0, a2 = a0, a3 = a0, a4 = a0;

    int i = beg;
    for (; i + 1 < end; i += 2) {
        const float2* r0 = (const float2*)(x + (size_t)elist[i] * IN_C);
        const float2* r1 = (const float2*)(x + (size_t)elist[i + 1] * IN_C);
        float2 v0 = r0[lane],       w0 = r1[lane];
        float2 v1 = r0[lane + 64],  w1 = r1[lane + 64];
        float2 v2 = r0[lane + 128], w2 = r1[lane + 128];
        float2 v3 = r0[lane + 192], w3 = r1[lane + 192];
        a0.x += v0.x + w0.x; a0.y += v0.y + w0.y;
        a1.x += v1.x + w1.x; a1.y += v1.y + w1.y;
        a2.x += v2.x + w2.x; a2.y += v2.y + w2.y;
        a3.x += v3.x + w3.x; a3.y += v3.y + w3.y;
        if (lane < 45) {
            float2 v4 = r0[lane + 256], w4 = r1[lane + 256];
            a4.x += v4.x + w4.x; a4.y += v4.y + w4.y;
        }
    }
    if (i < end) {
        const float2* r0 = (const float2*)(x + (size_t)elist[i] * IN_C);
        float2 v0 = r0[lane], v1 = r0[lane + 64], v2 = r0[lane + 128], v3 = r0[lane + 192];
        a0.x += v0.x; a0.y += v0.y;
        a1.x += v1.x; a1.y += v1.y;
        a2.x += v2.x; a2.y += v2.y;
        a3.x += v3.x; a3.y += v3.y;
        if (lane < 45) {
            float2 v4 = r0[lane + 256];
            a4.x += v4.x; a4.y += v4.y;
        }
    }

    int d = end - beg;
    float inv = 1.0f / (float)(d > 1 ? d : 1);
    ushort2* orow = (ushort2*)(A + (size_t)t * KTOT);
    ushort2 o;
    o.x = f2bf(a0.x * inv); o.y = f2bf(a0.y * inv); orow[lane]       = o;
    o.x = f2bf(a1.x * inv); o.y = f2bf(a1.y * inv); orow[lane + 64]  = o;
    o.x = f2bf(a2.x * inv); o.y = f2bf(a2.y * inv); orow[lane + 128] = o;
    o.x = f2bf(a3.x * inv); o.y = f2bf(a3.y * inv); orow[lane + 192] = o;
    if (lane < 45) {
        o.x = f2bf(a4.x * inv); o.y = f2bf(a4.y * inv); orow[lane + 256] = o;
    } else if (lane < 48) {  // pad cols 602..607 -> zero
        o.x = 0; o.y = 0; orow[lane + 256] = o;
    }
}

// ---------------- cast x[:10240] -> bf16 into A cols 608..1215 ----------------
__global__ void cast_x_kernel(const float* __restrict__ x, u16* __restrict__ A) {
    int id = blockIdx.x * blockDim.x + threadIdx.x;
    if (id >= N_TGT0 * 304) return;
    int r = id / 304;
    int j = (id - r * 304) * 2;   // 0..606, even
    float2 v = make_float2(0.f, 0.f);
    if (j < IN_C) v = *(const float2*)(x + (size_t)r * IN_C + j);
    ushort2 o; o.x = f2bf(v.x); o.y = f2bf(v.y);
    *(ushort2*)(A + (size_t)r * KTOT + 608 + j) = o;
}

// ---------------- cast weights -> BT[n][k] bf16 (B transposed) ----------------
__global__ void cast_w_kernel(const float* __restrict__ Wl, const float* __restrict__ Wr,
                              u16* __restrict__ BT) {
    int id = blockIdx.x * blockDim.x + threadIdx.x;
    if (id >= HID_C * KTOT) return;
    int n = id / KTOT, k = id - n * KTOT;
    float v = 0.f;
    if (k < IN_C)                     v = Wl[(size_t)k * HID_C + n];
    else if (k >= 608 && k < 608 + IN_C) v = Wr[(size_t)(k - 608) * HID_C + n];
    BT[id] = f2bf(v);
}

// ---------------- fused layer-1 GEMM: h = relu(A @ B + b1), bf16 MFMA ----------------
// tile 128(M) x 64(N), BK=32, 4 waves (each 32x64), 16x16x32 MFMA
#define GBM 128
#define GBN 64
#define GBK 32
#define LDSS 40   // 32 + 8 pad (bf16 elems) -> 80B row stride, 2-way conflicts max

__global__ __launch_bounds__(256) void gemm1_mfma(
    const u16* __restrict__ A, const u16* __restrict__ BT,
    const float* __restrict__ bias, float* __restrict__ h)
{
    __shared__ u16 As[GBM * LDSS];
    __shared__ u16 Bs[GBN * LDSS];
    int tid = threadIdx.x;
    int wave = tid >> 6, lane = tid & 63;
    int bm = blockIdx.x * GBM;
    int bn = blockIdx.y * GBN;
    int r16 = lane & 15;
    int k8 = (lane >> 4) * 8;

    f32x4 acc[2][4] = {};

    for (int k0 = 0; k0 < KTOT; k0 += GBK) {
        __syncthreads();
        #pragma unroll
        for (int i = 0; i < 2; ++i) {
            int idx = tid + i * 256;          // 0..511
            int m = idx >> 2, seg = idx & 3;
            *(uint4*)(As + m * LDSS + seg * 8) =
                *(const uint4*)(A + (size_t)(bm + m) * KTOT + k0 + seg * 8);
        }
        {
            int n = tid >> 2, seg = tid & 3;
            *(uint4*)(Bs + n * LDSS + seg * 8) =
                *(const uint4*)(BT + (size_t)(bn + n) * KTOT + k0 + seg * 8);
        }
        __syncthreads();

        bf16x8 af[2], bfr[4];
        #pragma unroll
        for (int fm = 0; fm < 2; ++fm)
            af[fm] = *(const bf16x8*)(As + (wave * 32 + fm * 16 + r16) * LDSS + k8);
        #pragma unroll
        for (int fn = 0; fn < 4; ++fn)
            bfr[fn] = *(const bf16x8*)(Bs + (fn * 16 + r16) * LDSS + k8);
        #pragma unroll
        for (int fm = 0; fm < 2; ++fm)
            #pragma unroll
            for (int fn = 0; fn < 4; ++fn)
                acc[fm][fn] = __builtin_amdgcn_mfma_f32_16x16x32_bf16(
                    af[fm], bfr[fn], acc[fm][fn], 0, 0, 0);
    }

    int orow = bm + wave * 32 + (lane >> 4) * 4;
    #pragma unroll
    for (int fn = 0; fn < 4; ++fn) {
        int n = bn + fn * 16 + r16;
        float b = bias[n];
        #pragma unroll
        for (int fm = 0; fm < 2; ++fm) {
            #pragma unroll
            for (int j = 0; j < 4; ++j) {
                int m = orow + fm * 16 + j;
                float v = acc[fm][fn][j] + b;
                h[(size_t)m * HID_C + n] = v > 0.f ? v : 0.f;
            }
        }
    }
}

// ---------------- layer-2 aggregation (atomic scatter) ----------------

__global__ void agg1_scatter_kernel(const float* __restrict__ h, const int* __restrict__ src,
                                    const int* __restrict__ dst, float* __restrict__ agg, int E) {
    long i = blockIdx.x * (long)blockDim.x + threadIdx.x;
    if (i < (long)E * HID_C) {
        int e = (int)(i >> 8);
        int c = (int)(i & 255);
        atomicAdd(&agg[(long)dst[e] * HID_C + c], h[(long)src[e] * HID_C + c]);
    }
}

__global__ void agg1_div_kernel(float* __restrict__ agg, const int* __restrict__ cnt) {
    int t = blockIdx.x;
    int d = cnt[t];
    float inv = 1.0f / (float)(d > 1 ? d : 1);
    agg[(long)t * HID_C + threadIdx.x] *= inv;
}

// ---------------- layer-2 GEMM + log_softmax fused ----------------
__global__ __launch_bounds__(64) void out_kernel(
    const float* __restrict__ agg, const float* __restrict__ h,
    const float* __restrict__ Wl, const float* __restrict__ Wr,
    const float* __restrict__ bias, float* __restrict__ out)
{
    __shared__ float arow[HID_C];
    __shared__ float hrow[HID_C];
    __shared__ float o[OUT_C];
    __shared__ float lse;
    int t = blockIdx.x;
    int tid = threadIdx.x;

    for (int i = tid; i < HID_C; i += 64) {
        arow[i] = agg[(long)t * HID_C + i];
        hrow[i] = h[(long)t * HID_C + i];
    }
    __syncthreads();

    if (tid < OUT_C) {
        float v = bias[tid];
        for (int k = 0; k < HID_C; ++k)
            v += arow[k] * Wl[k * OUT_C + tid] + hrow[k] * Wr[k * OUT_C + tid];
        o[tid] = v;
    }
    __syncthreads();
    if (tid == 0) {
        float mx = o[0];
        for (int i = 1; i < OUT_C; ++i) mx = fmaxf(mx, o[i]);
        float s = 0.f;
        for (int i = 0; i < OUT_C; ++i) s += expf(o[i] - mx);
        lse = mx + logf(s);
    }
    __syncthreads();
    if (tid < OUT_C) out[(long)t * OUT_C + tid] = o[tid] - lse;
}

// ---------------- launch ----------------

extern "C" void kernel_launch(void* const* d_in, const int* in_sizes, int n_in,
                              void* d_out, int out_size, void* d_ws, size_t ws_size,
                              hipStream_t stream) {
    const float* x    = (const float*)d_in[0];
    const int*   src0 = (const int*)d_in[1];
    const int*   dst0 = (const int*)d_in[2];
    const int*   src1 = (const int*)d_in[3];
    const int*   dst1 = (const int*)d_in[4];
    const float* Wl1  = (const float*)d_in[5];
    const float* Wr1  = (const float*)d_in[6];
    const float* b1   = (const float*)d_in[7];
    const float* Wl2  = (const float*)d_in[8];
    const float* Wr2  = (const float*)d_in[9];
    const float* b2   = (const float*)d_in[10];
    float* out = (float*)d_out;

    // workspace layout (256B aligned chunks)
    char* ws = (char*)d_ws;
    size_t off = 0;
    auto take = [&](size_t bytes) { void* p = ws + off; off += (bytes + 255) & ~(size_t)255; return p; };
    u16*   A     = (u16*)  take((size_t)N_TGT0 * KTOT * 2);   // fused [agg | x_tgt] bf16
    u16*   BT    = (u16*)  take((size_t)HID_C * KTOT * 2);    // [Wl1; Wr1]^T bf16
    float* h     = (float*)take((size_t)N_TGT0 * HID_C * 4);
    float* agg1  = (float*)take((size_t)N_TGT1 * HID_C * 4);
    int*   cnt0    = (int*)take(N_TGT0 * 4);
    int*   rowptr0 = (int*)take((N_TGT0 + 1) * 4);
    int*   cursor0 = (int*)take(N_TGT0 * 4);
    int*   elist0  = (int*)take((size_t)E0 * 4);
    int*   cnt1    = (int*)take(N_TGT1 * 4);

    hipMemsetAsync(cnt0, 0, N_TGT0 * sizeof(int), stream);
    hipMemsetAsync(cnt1, 0, N_TGT1 * sizeof(int), stream);
    hipMemsetAsync(agg1, 0, (size_t)N_TGT1 * HID_C * sizeof(float), stream);

    count_kernel<<<(E0 + 255) / 256, 256, 0, stream>>>(dst0, cnt0, E0);
    scan_kernel<<<1, 256, 0, stream>>>(cnt0, rowptr0, cursor0, N_TGT0);
    scatter_kernel<<<(E0 + 255) / 256, 256, 0, stream>>>(src0, dst0, cursor0, elist0, E0);

    cast_x_kernel<<<(N_TGT0 * 304 + 255) / 256, 256, 0, stream>>>(x, A);
    cast_w_kernel<<<(HID_C * KTOT + 255) / 256, 256, 0, stream>>>(Wl1, Wr1, BT);

    agg0_kernel<<<N_TGT0 / 4, 256, 0, stream>>>(x, rowptr0, elist0, A);

    gemm1_mfma<<<dim3(N_TGT0 / GBM, HID_C / GBN), 256, 0, stream>>>(A, BT, b1, h);

    count_kernel<<<(E1 + 255) / 256, 256, 0, stream>>>(dst1, cnt1, E1);
    agg1_scatter_kernel<<<(int)(((long)E1 * HID_C + 255) / 256), 256, 0, stream>>>(h, src1, dst1, agg1, E1);
    agg1_div_kernel<<<N_TGT1, HID_C, 0, stream>>>(agg1, cnt1);

    out_kernel<<<N_TGT1, 64, 0, stream>>>(agg1, h, Wl2, Wr2, b2, out);
}

// Round 3
// 253.072 us; speedup vs baseline: 1.8888x; 1.0120x over previous
//
#include <hip/hip_runtime.h>
#include <hip/hip_bf16.h>

#define IN_C   602
#define HID_C  256
#define OUT_C  41
#define N_TGT0 10240
#define N_TGT1 1024
#define E0     256000
#define E1     10240
#define KTOT   1216   // 608 (agg, padded) + 608 (x_tgt, padded)

typedef unsigned short u16;
typedef __attribute__((ext_vector_type(4))) float f32x4;
typedef __attribute__((ext_vector_type(8))) short bf16x8;

__device__ __forceinline__ u16 f2bf(float v) {
    union { float f; unsigned u; } c; c.f = v;
    unsigned u = c.u;
    u += 0x7fffu + ((u >> 16) & 1u);   // round-to-nearest-even
    return (u16)(u >> 16);
}

// ---------------- CSR build (both layers) ----------------

__global__ void count_both(const int* __restrict__ dst0, const int* __restrict__ dst1,
                           int* __restrict__ cnt0, int* __restrict__ cnt1) {
    int e = blockIdx.x * blockDim.x + threadIdx.x;
    if (e < E0) atomicAdd(&cnt0[dst0[e]], 1);
    else if (e < E0 + E1) atomicAdd(&cnt1[dst1[e - E0]], 1);
}

// block 0: layer-1 (n=10240); block 1: layer-2 (n=1024)
__global__ void scan_both(const int* __restrict__ cnt0, int* __restrict__ rowptr0,
                          int* __restrict__ cursor0,
                          const int* __restrict__ cnt1, int* __restrict__ rowptr1,
                          int* __restrict__ cursor1) {
    const int* cnt; int* rowptr; int* cursor; int n;
    if (blockIdx.x == 0) { cnt = cnt0; rowptr = rowptr0; cursor = cursor0; n = N_TGT0; }
    else                 { cnt = cnt1; rowptr = rowptr1; cursor = cursor1; n = N_TGT1; }
    __shared__ int part[256];
    int t = threadIdx.x;
    int chunk = (n + 255) / 256;
    int beg = t * chunk;
    int end = beg + chunk; if (end > n) end = n;
    int s = 0;
    for (int i = beg; i < end; ++i) s += cnt[i];
    part[t] = s;
    __syncthreads();
    if (t == 0) {
        int run = 0;
        for (int i = 0; i < 256; ++i) { int v = part[i]; part[i] = run; run += v; }
        rowptr[n] = run;
    }
    __syncthreads();
    int run = part[t];
    for (int i = beg; i < end; ++i) {
        rowptr[i] = run;
        cursor[i] = run;
        run += cnt[i];
    }
}

__global__ void scatter_both(const int* __restrict__ src0, const int* __restrict__ dst0,
                             int* __restrict__ cursor0, int* __restrict__ elist0,
                             const int* __restrict__ src1, const int* __restrict__ dst1,
                             int* __restrict__ cursor1, int* __restrict__ elist1) {
    int e = blockIdx.x * blockDim.x + threadIdx.x;
    if (e < E0) {
        int p = atomicAdd(&cursor0[dst0[e]], 1);
        elist0[p] = src0[e];
    } else if (e < E0 + E1) {
        int i = e - E0;
        int p = atomicAdd(&cursor1[dst1[i]], 1);
        elist1[p] = src1[i];
    }
}

// ---------------- layer-1 aggregation + x_tgt cast, fused ----------------
// one wave per target; row = 301 float2 slots; lane l owns slots l, l+64, l+128,
// l+192, and (l<45) slot 256+l. Writes bf16 into A[t][0..607] (agg, padded)
// and A[t][608..1215] (x[t], padded).
__global__ __launch_bounds__(256) void agg0_fused(
    const float* __restrict__ x, const int* __restrict__ rowptr,
    const int* __restrict__ elist, u16* __restrict__ A)
{
    int t = blockIdx.x * 4 + (threadIdx.x >> 6);
    int lane = threadIdx.x & 63;
    int beg = rowptr[t], end = rowptr[t + 1];

    float2 a0 = make_float2(0.f, 0.f), a1 = a0, a2 = a0, a3 = a0, a4 = a0;

    int i = beg;
    for (; i + 3 < end; i += 4) {
        const float2* rp[4];
        #pragma unroll
        for (int u = 0; u < 4; ++u)
            rp[u] = (const float2*)(x + (size_t)elist[i + u] * IN_C);
        #pragma unroll
        for (int u = 0; u < 4; ++u) {
            float2 v0 = rp[u][lane], v1 = rp[u][lane + 64];
            float2 v2 = rp[u][lane + 128], v3 = rp[u][lane + 192];
            a0.x += v0.x; a0.y += v0.y;
            a1.x += v1.x; a1.y += v1.y;
            a2.x += v2.x; a2.y += v2.y;
            a3.x += v3.x; a3.y += v3.y;
            if (lane < 45) {
                float2 v4 = rp[u][lane + 256];
                a4.x += v4.x; a4.y += v4.y;
            }
        }
    }
    for (; i < end; ++i) {
        const float2* r0 = (const float2*)(x + (size_t)elist[i] * IN_C);
        float2 v0 = r0[lane], v1 = r0[lane + 64], v2 = r0[lane + 128], v3 = r0[lane + 192];
        a0.x += v0.x; a0.y += v0.y;
        a1.x += v1.x; a1.y += v1.y;
        a2.x += v2.x; a2.y += v2.y;
        a3.x += v3.x; a3.y += v3.y;
        if (lane < 45) {
            float2 v4 = r0[lane + 256];
            a4.x += v4.x; a4.y += v4.y;
        }
    }

    int d = end - beg;
    float inv = 1.0f / (float)(d > 1 ? d : 1);
    ushort2* orow = (ushort2*)(A + (size_t)t * KTOT);
    ushort2 o;
    o.x = f2bf(a0.x * inv); o.y = f2bf(a0.y * inv); orow[lane]       = o;
    o.x = f2bf(a1.x * inv); o.y = f2bf(a1.y * inv); orow[lane + 64]  = o;
    o.x = f2bf(a2.x * inv); o.y = f2bf(a2.y * inv); orow[lane + 128] = o;
    o.x = f2bf(a3.x * inv); o.y = f2bf(a3.y * inv); orow[lane + 192] = o;
    if (lane < 45) {
        o.x = f2bf(a4.x * inv); o.y = f2bf(a4.y * inv); orow[lane + 256] = o;
    } else if (lane < 48) {   // pad cols 602..607
        o.x = 0; o.y = 0; orow[lane + 256] = o;
    }

    // x_tgt cast into cols 608..1215
    const float2* xt = (const float2*)(x + (size_t)t * IN_C);
    ushort2* orow2 = orow + 304;
    float2 w0 = xt[lane], w1 = xt[lane + 64], w2 = xt[lane + 128], w3 = xt[lane + 192];
    o.x = f2bf(w0.x); o.y = f2bf(w0.y); orow2[lane]       = o;
    o.x = f2bf(w1.x); o.y = f2bf(w1.y); orow2[lane + 64]  = o;
    o.x = f2bf(w2.x); o.y = f2bf(w2.y); orow2[lane + 128] = o;
    o.x = f2bf(w3.x); o.y = f2bf(w3.y); orow2[lane + 192] = o;
    if (lane < 45) {
        float2 w4 = xt[lane + 256];
        o.x = f2bf(w4.x); o.y = f2bf(w4.y); orow2[lane + 256] = o;
    } else if (lane < 48) {   // pad cols 1210..1215
        o.x = 0; o.y = 0; orow2[lane + 256] = o;
    }
}

// ---------------- weights -> BT[n][k] bf16 (B transposed, zero-padded) ----------------
__global__ void cast_w_kernel(const float* __restrict__ Wl, const float* __restrict__ Wr,
                              u16* __restrict__ BT) {
    int id = blockIdx.x * blockDim.x + threadIdx.x;
    if (id >= HID_C * KTOT) return;
    int n = id / KTOT, k = id - n * KTOT;
    float v = 0.f;
    if (k < IN_C)                        v = Wl[(size_t)k * HID_C + n];
    else if (k >= 608 && k < 608 + IN_C) v = Wr[(size_t)(k - 608) * HID_C + n];
    BT[id] = f2bf(v);
}

// ---------------- layer-1 GEMM: h = relu(A @ B + b1), bf16 MFMA ----------------
// tile 128(M) x 64(N), BK=64, 4 waves (each 32x64), 16x16x32 MFMA
#define GBM 128
#define GBN 64
#define GBK 64
#define LDSS 72   // 64 + 8 pad (bf16) -> 144B row stride, 2-way conflicts only

__global__ __launch_bounds__(256) void gemm1_mfma(
    const u16* __restrict__ A, const u16* __restrict__ BT,
    const float* __restrict__ bias, float* __restrict__ h)
{
    __shared__ u16 As[GBM * LDSS];
    __shared__ u16 Bs[GBN * LDSS];
    int tid = threadIdx.x;
    int wave = tid >> 6, lane = tid & 63;
    int bm = blockIdx.x * GBM;
    int bn = blockIdx.y * GBN;
    int r16 = lane & 15;
    int k8 = (lane >> 4) * 8;

    f32x4 acc[2][4] = {};

    for (int k0 = 0; k0 < KTOT; k0 += GBK) {
        __syncthreads();
        #pragma unroll
        for (int i = 0; i < 4; ++i) {       // A: 128 rows x 8 segs = 1024 chunks
            int idx = tid + i * 256;
            int m = idx >> 3, seg = idx & 7;
            *(uint4*)(As + m * LDSS + seg * 8) =
                *(const uint4*)(A + (size_t)(bm + m) * KTOT + k0 + seg * 8);
        }
        #pragma unroll
        for (int i = 0; i < 2; ++i) {       // B: 64 rows x 8 segs = 512 chunks
            int idx = tid + i * 256;
            int n = idx >> 3, seg = idx & 7;
            *(uint4*)(Bs + n * LDSS + seg * 8) =
                *(const uint4*)(BT + (size_t)(bn + n) * KTOT + k0 + seg * 8);
        }
        __syncthreads();

        #pragma unroll
        for (int ks = 0; ks < 2; ++ks) {
            int ko = ks * 32 + k8;
            bf16x8 af[2], bfr[4];
            #pragma unroll
            for (int fm = 0; fm < 2; ++fm)
                af[fm] = *(const bf16x8*)(As + (wave * 32 + fm * 16 + r16) * LDSS + ko);
            #pragma unroll
            for (int fn = 0; fn < 4; ++fn)
                bfr[fn] = *(const bf16x8*)(Bs + (fn * 16 + r16) * LDSS + ko);
            #pragma unroll
            for (int fm = 0; fm < 2; ++fm)
                #pragma unroll
                for (int fn = 0; fn < 4; ++fn)
                    acc[fm][fn] = __builtin_amdgcn_mfma_f32_16x16x32_bf16(
                        af[fm], bfr[fn], acc[fm][fn], 0, 0, 0);
        }
    }

    int orow = bm + wave * 32 + (lane >> 4) * 4;
    #pragma unroll
    for (int fn = 0; fn < 4; ++fn) {
        int n = bn + fn * 16 + r16;
        float b = bias[n];
        #pragma unroll
        for (int fm = 0; fm < 2; ++fm) {
            #pragma unroll
            for (int j = 0; j < 4; ++j) {
                int m = orow + fm * 16 + j;
                float v = acc[fm][fn][j] + b;
                h[(size_t)m * HID_C + n] = v > 0.f ? v : 0.f;
            }
        }
    }
}

// ---------------- layer-2: CSR pull + GEMM2 + log_softmax, fully fused ----------------
// one wave per output row
__global__ __launch_bounds__(64) void out_fused(
    const float* __restrict__ h, const int* __restrict__ rowptr,
    const int* __restrict__ elist, const float* __restrict__ Wl,
    const float* __restrict__ Wr, const float* __restrict__ bias,
    float* __restrict__ out)
{
    __shared__ float arow[HID_C];
    __shared__ float hrow[HID_C];
    int t = blockIdx.x;
    int lane = threadIdx.x;
    int beg = rowptr[t], end = rowptr[t + 1];

    float4 acc = make_float4(0.f, 0.f, 0.f, 0.f);
    for (int i = beg; i < end; ++i) {
        float4 v = ((const float4*)(h + (size_t)elist[i] * HID_C))[lane];
        acc.x += v.x; acc.y += v.y; acc.z += v.z; acc.w += v.w;
    }
    int d = end - beg;
    float inv = 1.0f / (float)(d > 1 ? d : 1);
    ((float4*)arow)[lane] = make_float4(acc.x * inv, acc.y * inv, acc.z * inv, acc.w * inv);
    ((float4*)hrow)[lane] = ((const float4*)(h + (size_t)t * HID_C))[lane];
    __syncthreads();

    float v = 0.f;
    if (lane < OUT_C) {
        v = bias[lane];
        for (int k = 0; k < HID_C; ++k)
            v += arow[k] * Wl[k * OUT_C + lane] + hrow[k] * Wr[k * OUT_C + lane];
    }
    float m = (lane < OUT_C) ? v : -1e30f;
    #pragma unroll
    for (int off = 32; off; off >>= 1) m = fmaxf(m, __shfl_xor(m, off));
    float ex = (lane < OUT_C) ? expf(v - m) : 0.f;
    float s = ex;
    #pragma unroll
    for (int off = 32; off; off >>= 1) s += __shfl_xor(s, off);
    float lse = m + logf(s);
    if (lane < OUT_C) out[(size_t)t * OUT_C + lane] = v - lse;
}

// ---------------- launch ----------------

extern "C" void kernel_launch(void* const* d_in, const int* in_sizes, int n_in,
                              void* d_out, int out_size, void* d_ws, size_t ws_size,
                              hipStream_t stream) {
    const float* x    = (const float*)d_in[0];
    const int*   src0 = (const int*)d_in[1];
    const int*   dst0 = (const int*)d_in[2];
    const int*   src1 = (const int*)d_in[3];
    const int*   dst1 = (const int*)d_in[4];
    const float* Wl1  = (const float*)d_in[5];
    const float* Wr1  = (const float*)d_in[6];
    const float* b1   = (const float*)d_in[7];
    const float* Wl2  = (const float*)d_in[8];
    const float* Wr2  = (const float*)d_in[9];
    const float* b2   = (const float*)d_in[10];
    float* out = (float*)d_out;

    char* ws = (char*)d_ws;
    size_t off = 0;
    auto take = [&](size_t bytes) { void* p = ws + off; off += (bytes + 255) & ~(size_t)255; return p; };
    u16*   A       = (u16*)  take((size_t)N_TGT0 * KTOT * 2);
    u16*   BT      = (u16*)  take((size_t)HID_C * KTOT * 2);
    float* h       = (float*)take((size_t)N_TGT0 * HID_C * 4);
    int*   cnt0    = (int*)  take((size_t)(N_TGT0 + N_TGT1) * 4);  // cnt0 | cnt1 contiguous
    int*   cnt1    = cnt0 + N_TGT0;
    int*   rowptr0 = (int*)  take((N_TGT0 + 1) * 4);
    int*   cursor0 = (int*)  take(N_TGT0 * 4);
    int*   elist0  = (int*)  take((size_t)E0 * 4);
    int*   rowptr1 = (int*)  take((N_TGT1 + 1) * 4);
    int*   cursor1 = (int*)  take(N_TGT1 * 4);
    int*   elist1  = (int*)  take((size_t)E1 * 4);

    hipMemsetAsync(cnt0, 0, (size_t)(N_TGT0 + N_TGT1) * sizeof(int), stream);

    count_both<<<(E0 + E1 + 255) / 256, 256, 0, stream>>>(dst0, dst1, cnt0, cnt1);
    scan_both<<<2, 256, 0, stream>>>(cnt0, rowptr0, cursor0, cnt1, rowptr1, cursor1);
    scatter_both<<<(E0 + E1 + 255) / 256, 256, 0, stream>>>(
        src0, dst0, cursor0, elist0, src1, dst1, cursor1, elist1);

    cast_w_kernel<<<(HID_C * KTOT + 255) / 256, 256, 0, stream>>>(Wl1, Wr1, BT);

    agg0_fused<<<N_TGT0 / 4, 256, 0, stream>>>(x, rowptr0, elist0, A);

    gemm1_mfma<<<dim3(N_TGT0 / GBM, HID_C / GBN), 256, 0, stream>>>(A, BT, b1, h);

    out_fused<<<N_TGT1, 64, 0, stream>>>(h, rowptr1, elist1, Wl2, Wr2, b2, out);
}

// Round 4
// 227.984 us; speedup vs baseline: 2.0966x; 1.1100x over previous
//
#include <hip/hip_runtime.h>
#include <hip/hip_bf16.h>

#define IN_C   602
#define HID_C  256
#define OUT_C  41
#define N_TGT0 10240
#define N_TGT1 1024
#define E0     256000
#define E1     10240
#define KTOT   1216   // 608 (agg, padded) + 608 (x_tgt, padded)
#define NWK    (HID_C * KTOT)   // 311296 weight-cast items (> E0+E1)

typedef unsigned short u16;
typedef __attribute__((ext_vector_type(4))) float f32x4;
typedef __attribute__((ext_vector_type(8))) short bf16x8;

__device__ __forceinline__ u16 f2bf(float v) {
    union { float f; unsigned u; } c; c.f = v;
    unsigned u = c.u;
    u += 0x7fffu + ((u >> 16) & 1u);   // round-to-nearest-even
    return (u16)(u >> 16);
}
__device__ __forceinline__ float bf2f(u16 v) {
    union { unsigned u; float f; } c; c.u = ((unsigned)v) << 16; return c.f;
}

// ---------------- build: linked-list adjacency (both layers) + weight cast ----------------
__global__ __launch_bounds__(256) void build_kernel(
    const int* __restrict__ src0, const int* __restrict__ dst0,
    const int* __restrict__ src1, const int* __restrict__ dst1,
    int* __restrict__ head0, int* __restrict__ next0,
    int* __restrict__ head1, int* __restrict__ next1,
    const float* __restrict__ Wl, const float* __restrict__ Wr, u16* __restrict__ BT)
{
    int id = blockIdx.x * 256 + threadIdx.x;
    if (id < E0) {
        int p = atomicExch(&head0[dst0[id]], id);
        next0[id] = p;
    } else if (id < E0 + E1) {
        int e = id - E0;
        int p = atomicExch(&head1[dst1[e]], e);
        next1[e] = p;
    }
    if (id < NWK) {
        int n = id / KTOT, k = id - n * KTOT;
        float v = 0.f;
        if (k < IN_C)                        v = Wl[(size_t)k * HID_C + n];
        else if (k >= 608 && k < 608 + IN_C) v = Wr[(size_t)(k - 608) * HID_C + n];
        BT[id] = f2bf(v);
    }
}

// ---------------- layer-1 aggregation (linked-list walk) + x_tgt cast ----------------
// one wave per target; row = 301 float2 slots; lane l owns slots l, l+64, l+128,
// l+192, and (l<45) slot 256+l. Chain loads for edge i+1 issued during edge i's
// row gather (latency hidden); BW comes from TLP (10240 waves).
__global__ __launch_bounds__(256) void agg0_ll(
    const float* __restrict__ x, const int* __restrict__ head,
    const int* __restrict__ next, const int* __restrict__ srcv,
    u16* __restrict__ A)
{
    int t = blockIdx.x * 4 + (threadIdx.x >> 6);
    int lane = threadIdx.x & 63;

    float2 a0 = make_float2(0.f, 0.f), a1 = a0, a2 = a0, a3 = a0, a4 = a0;
    int d = 0;

    int cur = head[t];
    int s   = (cur >= 0) ? srcv[cur] : 0;
    int nxt = (cur >= 0) ? next[cur] : -1;
    while (cur >= 0) {
        const float2* r = (const float2*)(x + (size_t)s * IN_C);
        float2 v0 = r[lane], v1 = r[lane + 64], v2 = r[lane + 128], v3 = r[lane + 192];
        // prefetch next edge's chain while rows are in flight
        int curN = nxt;
        int sN   = (curN >= 0) ? srcv[curN] : 0;
        int nxtN = (curN >= 0) ? next[curN] : -1;
        a0.x += v0.x; a0.y += v0.y;
        a1.x += v1.x; a1.y += v1.y;
        a2.x += v2.x; a2.y += v2.y;
        a3.x += v3.x; a3.y += v3.y;
        if (lane < 45) {
            float2 v4 = r[lane + 256];
            a4.x += v4.x; a4.y += v4.y;
        }
        ++d;
        cur = curN; s = sN; nxt = nxtN;
    }

    float inv = 1.0f / (float)(d > 1 ? d : 1);
    ushort2* orow = (ushort2*)(A + (size_t)t * KTOT);
    ushort2 o;
    o.x = f2bf(a0.x * inv); o.y = f2bf(a0.y * inv); orow[lane]       = o;
    o.x = f2bf(a1.x * inv); o.y = f2bf(a1.y * inv); orow[lane + 64]  = o;
    o.x = f2bf(a2.x * inv); o.y = f2bf(a2.y * inv); orow[lane + 128] = o;
    o.x = f2bf(a3.x * inv); o.y = f2bf(a3.y * inv); orow[lane + 192] = o;
    if (lane < 45) {
        o.x = f2bf(a4.x * inv); o.y = f2bf(a4.y * inv); orow[lane + 256] = o;
    } else if (lane < 48) {   // pad cols 602..607
        o.x = 0; o.y = 0; orow[lane + 256] = o;
    }

    // x_tgt cast into cols 608..1215
    const float2* xt = (const float2*)(x + (size_t)t * IN_C);
    ushort2* orow2 = orow + 304;
    float2 w0 = xt[lane], w1 = xt[lane + 64], w2 = xt[lane + 128], w3 = xt[lane + 192];
    o.x = f2bf(w0.x); o.y = f2bf(w0.y); orow2[lane]       = o;
    o.x = f2bf(w1.x); o.y = f2bf(w1.y); orow2[lane + 64]  = o;
    o.x = f2bf(w2.x); o.y = f2bf(w2.y); orow2[lane + 128] = o;
    o.x = f2bf(w3.x); o.y = f2bf(w3.y); orow2[lane + 192] = o;
    if (lane < 45) {
        float2 w4 = xt[lane + 256];
        o.x = f2bf(w4.x); o.y = f2bf(w4.y); orow2[lane + 256] = o;
    } else if (lane < 48) {   // pad cols 1210..1215
        o.x = 0; o.y = 0; orow2[lane + 256] = o;
    }
}

// ---------------- layer-1 GEMM: h = relu(A @ B + b1), bf16 MFMA, reg-dbuf ----------------
// tile 128(M) x 64(N), BK=64, 4 waves (each 32x64), 16x16x32 MFMA, bf16 output
#define GBM 128
#define GBN 64
#define GBK 64
#define NIT (KTOT / GBK)   // 19
#define LDSS 72            // 64 + 8 pad (bf16) -> 144B row stride, 2-way conflicts only

__global__ __launch_bounds__(256) void gemm1_mfma(
    const u16* __restrict__ A, const u16* __restrict__ BT,
    const float* __restrict__ bias, u16* __restrict__ h)
{
    __shared__ u16 As[GBM * LDSS];
    __shared__ u16 Bs[GBN * LDSS];
    int tid = threadIdx.x;
    int wave = tid >> 6, lane = tid & 63;
    int bm = blockIdx.x * GBM;
    int bn = blockIdx.y * GBN;
    int r16 = lane & 15;
    int k8 = (lane >> 4) * 8;

    // staging coords: A: idx = tid + i*256 (i<4), m=idx>>3, seg=idx&7
    //                 B: idx = tid + i*256 (i<2), n=idx>>3, seg=idx&7
    uint4 ra[4], rb[2];

    auto loadA = [&](int k0) {
        #pragma unroll
        for (int i = 0; i < 4; ++i) {
            int idx = tid + i * 256, m = idx >> 3, seg = idx & 7;
            ra[i] = *(const uint4*)(A + (size_t)(bm + m) * KTOT + k0 + seg * 8);
        }
    };
    auto loadB = [&](int k0) {
        #pragma unroll
        for (int i = 0; i < 2; ++i) {
            int idx = tid + i * 256, n = idx >> 3, seg = idx & 7;
            rb[i] = *(const uint4*)(BT + (size_t)(bn + n) * KTOT + k0 + seg * 8);
        }
    };
    auto storeLDS = [&]() {
        #pragma unroll
        for (int i = 0; i < 4; ++i) {
            int idx = tid + i * 256, m = idx >> 3, seg = idx & 7;
            *(uint4*)(As + m * LDSS + seg * 8) = ra[i];
        }
        #pragma unroll
        for (int i = 0; i < 2; ++i) {
            int idx = tid + i * 256, n = idx >> 3, seg = idx & 7;
            *(uint4*)(Bs + n * LDSS + seg * 8) = rb[i];
        }
    };

    f32x4 acc[2][4] = {};

    loadA(0); loadB(0);
    storeLDS();
    __syncthreads();

    for (int it = 0; it < NIT; ++it) {
        if (it + 1 < NIT) { loadA((it + 1) * GBK); loadB((it + 1) * GBK); }

        #pragma unroll
        for (int ks = 0; ks < 2; ++ks) {
            int ko = ks * 32 + k8;
            bf16x8 af[2], bfr[4];
            #pragma unroll
            for (int fm = 0; fm < 2; ++fm)
                af[fm] = *(const bf16x8*)(As + (wave * 32 + fm * 16 + r16) * LDSS + ko);
            #pragma unroll
            for (int fn = 0; fn < 4; ++fn)
                bfr[fn] = *(const bf16x8*)(Bs + (fn * 16 + r16) * LDSS + ko);
            #pragma unroll
            for (int fm = 0; fm < 2; ++fm)
                #pragma unroll
                for (int fn = 0; fn < 4; ++fn)
                    acc[fm][fn] = __builtin_amdgcn_mfma_f32_16x16x32_bf16(
                        af[fm], bfr[fn], acc[fm][fn], 0, 0, 0);
        }
        __syncthreads();
        if (it + 1 < NIT) {
            storeLDS();
            __syncthreads();
        }
    }

    int orow = bm + wave * 32 + (lane >> 4) * 4;
    #pragma unroll
    for (int fn = 0; fn < 4; ++fn) {
        int n = bn + fn * 16 + r16;
        float b = bias[n];
        #pragma unroll
        for (int fm = 0; fm < 2; ++fm) {
            #pragma unroll
            for (int j = 0; j < 4; ++j) {
                int m = orow + fm * 16 + j;
                float v = acc[fm][fn][j] + b;
                h[(size_t)m * HID_C + n] = f2bf(v > 0.f ? v : 0.f);
            }
        }
    }
}

// ---------------- layer-2: list pull + GEMM2 + log_softmax, fully fused ----------------
// one wave per output row; h is bf16
__global__ __launch_bounds__(64) void out_fused(
    const u16* __restrict__ h, const int* __restrict__ head,
    const int* __restrict__ next, const int* __restrict__ srcv,
    const float* __restrict__ Wl, const float* __restrict__ Wr,
    const float* __restrict__ bias, float* __restrict__ out)
{
    __shared__ float arow[HID_C];
    __shared__ float hrow[HID_C];
    int t = blockIdx.x;
    int lane = threadIdx.x;

    float4 acc = make_float4(0.f, 0.f, 0.f, 0.f);
    int d = 0;
    int cur = head[t];
    int s   = (cur >= 0) ? srcv[cur] : 0;
    int nxt = (cur >= 0) ? next[cur] : -1;
    while (cur >= 0) {
        ushort4 v = ((const ushort4*)(h + (size_t)s * HID_C))[lane];
        int curN = nxt;
        int sN   = (curN >= 0) ? srcv[curN] : 0;
        int nxtN = (curN >= 0) ? next[curN] : -1;
        acc.x += bf2f(v.x); acc.y += bf2f(v.y);
        acc.z += bf2f(v.z); acc.w += bf2f(v.w);
        ++d;
        cur = curN; s = sN; nxt = nxtN;
    }
    float inv = 1.0f / (float)(d > 1 ? d : 1);
    ((float4*)arow)[lane] = make_float4(acc.x * inv, acc.y * inv, acc.z * inv, acc.w * inv);
    ushort4 hv = ((const ushort4*)(h + (size_t)t * HID_C))[lane];
    ((float4*)hrow)[lane] = make_float4(bf2f(hv.x), bf2f(hv.y), bf2f(hv.z), bf2f(hv.w));
    __syncthreads();

    float v = 0.f;
    if (lane < OUT_C) {
        v = bias[lane];
        for (int k = 0; k < HID_C; ++k)
            v += arow[k] * Wl[k * OUT_C + lane] + hrow[k] * Wr[k * OUT_C + lane];
    }
    float m = (lane < OUT_C) ? v : -1e30f;
    #pragma unroll
    for (int off = 32; off; off >>= 1) m = fmaxf(m, __shfl_xor(m, off));
    float ex = (lane < OUT_C) ? expf(v - m) : 0.f;
    float sum = ex;
    #pragma unroll
    for (int off = 32; off; off >>= 1) sum += __shfl_xor(sum, off);
    float lse = m + logf(sum);
    if (lane < OUT_C) out[(size_t)t * OUT_C + lane] = v - lse;
}

// ---------------- launch ----------------

extern "C" void kernel_launch(void* const* d_in, const int* in_sizes, int n_in,
                              void* d_out, int out_size, void* d_ws, size_t ws_size,
                              hipStream_t stream) {
    const float* x    = (const float*)d_in[0];
    const int*   src0 = (const int*)d_in[1];
    const int*   dst0 = (const int*)d_in[2];
    const int*   src1 = (const int*)d_in[3];
    const int*   dst1 = (const int*)d_in[4];
    const float* Wl1  = (const float*)d_in[5];
    const float* Wr1  = (const float*)d_in[6];
    const float* b1   = (const float*)d_in[7];
    const float* Wl2  = (const float*)d_in[8];
    const float* Wr2  = (const float*)d_in[9];
    const float* b2   = (const float*)d_in[10];
    float* out = (float*)d_out;

    char* ws = (char*)d_ws;
    size_t off = 0;
    auto take = [&](size_t bytes) { void* p = ws + off; off += (bytes + 255) & ~(size_t)255; return p; };
    u16* A     = (u16*)take((size_t)N_TGT0 * KTOT * 2);   // fused [agg | x_tgt] bf16
    u16* BT    = (u16*)take((size_t)HID_C * KTOT * 2);    // [Wl1; Wr1]^T bf16
    u16* h     = (u16*)take((size_t)N_TGT0 * HID_C * 2);  // layer-1 output, bf16
    int* head0 = (int*)take((size_t)(N_TGT0 + N_TGT1) * 4);  // head0 | head1 contiguous
    int* head1 = head0 + N_TGT0;
    int* next0 = (int*)take((size_t)E0 * 4);
    int* next1 = (int*)take((size_t)E1 * 4);

    // heads = -1 (memset bytes 0xFF)
    hipMemsetAsync(head0, 0xFF, (size_t)(N_TGT0 + N_TGT1) * sizeof(int), stream);

    build_kernel<<<(NWK + 255) / 256, 256, 0, stream>>>(
        src0, dst0, src1, dst1, head0, next0, head1, next1, Wl1, Wr1, BT);

    agg0_ll<<<N_TGT0 / 4, 256, 0, stream>>>(x, head0, next0, src0, A);

    gemm1_mfma<<<dim3(N_TGT0 / GBM, HID_C / GBN), 256, 0, stream>>>(A, BT, b1, h);

    out_fused<<<N_TGT1, 64, 0, stream>>>(h, head1, next1, src1, Wl2, Wr2, b2, out);
}